// Round 3
// baseline (409.595 us; speedup 1.0000x reference)
//
#include <hip/hip_runtime.h>
#include <math.h>

#define B_ 8
#define T1_ 32
#define T2_ 32
#define T3_ 16
#define D_ 512
#define L_ 20
#define DL_ 128
#define M_ (B_*T1_*T2_*T3_)   // 131072

// workspace layout (float offsets)
#define WS_FW   0                      // B*L*DL = 20480
#define WS_KQ   20480                  // B*L*DL = 20480
#define WS_FS   40960                  // B*DL   = 1024
#define WS_SB   41984                  // B*L    = 160
#define WS_WDB  42144                  // Wc_down bf16: 65536 ushort
#define WS_WUB  74912                  // Wc_up   bf16: 65536 ushort

typedef __attribute__((ext_vector_type(8))) short short8_t;
typedef __attribute__((ext_vector_type(4))) float f32x4;

__device__ __forceinline__ unsigned short f2b(float f) {
  unsigned int u = __float_as_uint(f);
  return (unsigned short)((u + 0x7fffu + ((u >> 16) & 1u)) >> 16);
}
__device__ __forceinline__ float b2f(short s) {
  return __uint_as_float(((unsigned)(unsigned short)s) << 16);
}
__device__ __forceinline__ int4 pack8(float4 a, float4 b) {
  int4 p;
  p.x = (int)f2b(a.x) | ((int)f2b(a.y) << 16);
  p.y = (int)f2b(a.z) | ((int)f2b(a.w) << 16);
  p.z = (int)f2b(b.x) | ((int)f2b(b.y) << 16);
  p.w = (int)f2b(b.z) | ((int)f2b(b.w) << 16);
  return p;
}

// ---------------------------------------------------------------------------
// K0: convert Wc_down [128][512] and Wc_up [512][128] fp32 -> bf16 in ws
// ---------------------------------------------------------------------------
__global__ __launch_bounds__(256) void k0_convert(
    const float* __restrict__ Wd, const float* __restrict__ Wu,
    unsigned short* __restrict__ wdb, unsigned short* __restrict__ wub) {
  int g = blockIdx.x * 256 + threadIdx.x;      // 0..32767
  if (g < 16384) {
    float4 v = ((const float4*)Wd)[g];
    ushort4 h; h.x = f2b(v.x); h.y = f2b(v.y); h.z = f2b(v.z); h.w = f2b(v.w);
    ((ushort4*)wdb)[g] = h;
  } else {
    int q = g - 16384;
    float4 v = ((const float4*)Wu)[q];
    ushort4 h; h.x = f2b(v.x); h.y = f2b(v.y); h.z = f2b(v.z); h.w = f2b(v.w);
    ((ushort4*)wub)[q] = h;
  }
}

// ---------------------------------------------------------------------------
// K1: tiny projections. grid = B*L blocks, 128 threads.
// ---------------------------------------------------------------------------
__global__ __launch_bounds__(128) void k1_small(
    const float* __restrict__ f_w, const float* __restrict__ f_s,
    const float* __restrict__ Ww, const float* __restrict__ bw,
    const float* __restrict__ Ws, const float* __restrict__ bs,
    const float* __restrict__ Wq, const float* __restrict__ bq,
    const float* __restrict__ Wk, const float* __restrict__ bk,
    float* __restrict__ ws) {
  const int bl = blockIdx.x;
  const int b = bl / L_, l = bl % L_;
  const int d = threadIdx.x;
  __shared__ float s_fw[DL_];
  __shared__ float s_k[DL_];
  {
    const float* x = f_w + (size_t)(b*L_+l)*D_;
    const float* w = Ww + (size_t)d*D_;
    float acc = 0.f;
    for (int i = 0; i < D_; i += 4)
      acc += x[i]*w[i] + x[i+1]*w[i+1] + x[i+2]*w[i+2] + x[i+3]*w[i+3];
    acc += bw[d];
    s_fw[d] = acc;
    ws[WS_FW + (b*L_+l)*DL_ + d] = acc;
  }
  if (l == 0) {
    const float* x = f_s + (size_t)b*D_;
    const float* w = Ws + (size_t)d*D_;
    float acc = 0.f;
    for (int i = 0; i < D_; i += 4)
      acc += x[i]*w[i] + x[i+1]*w[i+1] + x[i+2]*w[i+2] + x[i+3]*w[i+3];
    ws[WS_FS + b*DL_ + d] = acc + bs[d];
  }
  __syncthreads();
  {
    const float* w = Wk + (size_t)d*DL_;
    float acc = 0.f;
    for (int i = 0; i < DL_; ++i) acc += s_fw[i]*w[i];
    s_k[d] = acc + bk[d];
  }
  __syncthreads();
  {
    float acc = 0.f;
    for (int c = 0; c < DL_; ++c) acc += s_k[c] * Wq[c*DL_ + d];
    ws[WS_KQ + (b*L_+l)*DL_ + d] = acc;
  }
  if (d == 0) {
    float acc = 0.f;
    for (int c = 0; c < DL_; ++c) acc += bq[c]*s_k[c];
    ws[WS_SB + b*L_ + l] = acc;
  }
}

// ---------------------------------------------------------------------------
// K2: fused per 32-row tile. Operand-swapped MFMA (A=weights, B=activations):
//  down GEMM: no LDS, no barriers (weights + f_c frags direct from global/L2)
//  middle: fp32 VALU with bf16-compressed kq/fw/f_cq in LDS
//  up GEMM: FCCH from LDS (B), wub from global (A); vectorized epilogue
// LDS = 39296 B -> 4 blocks/CU
// ---------------------------------------------------------------------------
// LDS float offsets
#define OF_FCH  0                 // [32][132] f32 = 4224 f
#define OF_KQB  4224              // [20][136] bf16 = 1360 f   (byte 16896)
#define OF_AC   4224              // [32][17] f32 = 544 f (aliases KQB, phase4+)
#define OF_FWB  5584              // [20][136] bf16 = 1360 f   (byte 22336)
#define OF_FS   6944              // 128 f
#define OF_SB   7072              // 32 f
#define OF_ATTN 7104              // [32][21] = 672 f
#define OF_FCQ  7776              // [32][256B] bf16 swizzled = 2048 f (also FCCH)
#define SMEM_F  9824              // 39296 bytes
#define KQB_B   (OF_KQB*4)
#define FWB_B   (OF_FWB*4)
#define FCQ_B   (OF_FCQ*4)

__global__ __launch_bounds__(256, 4) void k2_fused(
    const float* __restrict__ f_c, const unsigned short* __restrict__ wdb,
    const unsigned short* __restrict__ wub,
    const float* __restrict__ bc_down, const float* __restrict__ bc_up,
    const float* __restrict__ f_m, const float* __restrict__ f_s,
    const float* __restrict__ ws, float* __restrict__ out) {
  __shared__ float smem[SMEM_F];
  char* smb = (char*)smem;
  float* sFch = smem + OF_FCH;
  float* sAc  = smem + OF_AC;
  float* sFs  = smem + OF_FS;
  float* sSb  = smem + OF_SB;
  float* sAttn= smem + OF_ATTN;

  const int t = threadIdx.x;
  const int row0 = blockIdx.x * 32;
  const int b = row0 >> 14;
  const int lane = t & 63, w = t >> 6;
  const int l15 = lane & 15, l4 = lane >> 4;
  const int wr = (w & 1) * 16;        // N side: f_c-row group base
  const int wc = (w >> 1);            // M side: d-col group (0/1)
  const float inv_sqrt_dl = 0.08838834764831843f;
  const f32x4 z4 = {0.f, 0.f, 0.f, 0.f};

  // ---------------- down GEMM (no LDS, no barriers) ------------------------
  f32x4 dacc[4];
  #pragma unroll
  for (int cf = 0; cf < 4; ++cf) dacc[cf] = z4;
  {
    const float* fcb = f_c + (size_t)(row0 + wr + l15) * D_;
    for (int kc = 0; kc < D_; kc += 64) {
      #pragma unroll
      for (int ks = 0; ks < 2; ++ks) {
        const int k0 = kc + ks*32 + l4*8;
        float4 v0 = *(const float4*)(fcb + k0);
        float4 v1 = *(const float4*)(fcb + k0 + 4);
        int4 pk = pack8(v0, v1);
        short8_t bfrag = *(short8_t*)&pk;
        #pragma unroll
        for (int cf = 0; cf < 4; ++cf) {
          const int d = wc*64 + cf*16 + l15;
          short8_t afrag = *(const short8_t*)(wdb + (size_t)d*D_ + k0);
          dacc[cf] = __builtin_amdgcn_mfma_f32_16x16x32_bf16(afrag, bfrag, dacc[cf], 0, 0, 0);
        }
      }
    }
  }
  // writeout: lane holds rows (N)=wr+l15, d (M)=wc*64+cf*16+l4*4+r -> float4
  #pragma unroll
  for (int cf = 0; cf < 4; ++cf) {
    const int d0 = wc*64 + cf*16 + l4*4;
    float4 bias = *(const float4*)(bc_down + d0);
    float4 o;
    o.x = dacc[cf][0] + bias.x; o.y = dacc[cf][1] + bias.y;
    o.z = dacc[cf][2] + bias.z; o.w = dacc[cf][3] + bias.w;
    *(float4*)(sFch + (wr + l15)*132 + d0) = o;
  }
  // stage per-batch smalls (kq, fw -> bf16; fs, sb -> f32)
  for (int p = t; p < L_*16; p += 256) {      // 320 items
    const int l = p >> 4, c8 = (p & 15) * 8;
    float4 a0 = *(const float4*)(ws + WS_KQ + (b*L_+l)*DL_ + c8);
    float4 a1 = *(const float4*)(ws + WS_KQ + (b*L_+l)*DL_ + c8 + 4);
    *(int4*)(smb + KQB_B + l*272 + c8*2) = pack8(a0, a1);
    float4 b0 = *(const float4*)(ws + WS_FW + (b*L_+l)*DL_ + c8);
    float4 b1 = *(const float4*)(ws + WS_FW + (b*L_+l)*DL_ + c8 + 4);
    *(int4*)(smb + FWB_B + l*272 + c8*2) = pack8(b0, b1);
  }
  if (t < 32) *(float4*)(sFs + t*4) = *(const float4*)(ws + WS_FS + b*DL_ + t*4);
  if (t < L_) sSb[t] = ws[WS_SB + b*L_ + t];
  __syncthreads();

  // ---------------- phase2: scores + softmax over L ------------------------
  for (int p = t; p < 32*L_; p += 256) {
    const int r = p / L_, l = p - r*L_;
    const float* qr = sFch + r*132;
    const short* kr = (const short*)(smb + KQB_B + l*272);
    float s = 0.f;
    #pragma unroll
    for (int k = 0; k < DL_; k += 8) {
      short8_t kv = *(const short8_t*)(kr + k);
      float4 q0 = *(const float4*)(qr + k);
      float4 q1 = *(const float4*)(qr + k + 4);
      s += q0.x*b2f(kv[0]) + q0.y*b2f(kv[1]) + q0.z*b2f(kv[2]) + q0.w*b2f(kv[3])
         + q1.x*b2f(kv[4]) + q1.y*b2f(kv[5]) + q1.z*b2f(kv[6]) + q1.w*b2f(kv[7]);
    }
    sAttn[r*21 + l] = (s + sSb[l]) * inv_sqrt_dl;
  }
  __syncthreads();
  if (t < 32) {
    float* srow = sAttn + t*21;
    float m = -1e30f;
    for (int l = 0; l < L_; ++l) m = fmaxf(m, srow[l]);
    float sum = 0.f;
    for (int l = 0; l < L_; ++l) { float e = __expf(srow[l]-m); srow[l] = e; sum += e; }
    float inv = 1.f/sum;
    for (int l = 0; l < L_; ++l) srow[l] *= inv;
  }
  __syncthreads();
  // ---------------- phase3: f_cq -> bf16 swizzled LDS ----------------------
  for (int p = t; p < 1024; p += 256) {
    const int r = p >> 5, d4 = (p & 31) * 4;
    float ax = 0.f, ay = 0.f, az = 0.f, aw = 0.f;
    for (int l = 0; l < L_; ++l) {
      float a = sAttn[r*21 + l];
      ushort4 wv = *(const ushort4*)(smb + FWB_B + l*272 + d4*2);
      ax += a*b2f((short)wv.x); ay += a*b2f((short)wv.y);
      az += a*b2f((short)wv.z); aw += a*b2f((short)wv.w);
    }
    float4 fs4 = *(const float4*)(sFs + d4);
    float4 fh  = *(const float4*)(sFch + r*132 + d4);
    ushort4 pk;
    pk.x = f2b(fh.x*(ax+fs4.x)); pk.y = f2b(fh.y*(ay+fs4.y));
    pk.z = f2b(fh.z*(az+fs4.z)); pk.w = f2b(fh.w*(aw+fs4.w));
    *(ushort4*)(smb + FCQ_B + r*256 + ((d4*2) ^ ((r & 7) << 4))) = pk;
  }
  __syncthreads();
  // ---------------- phase4: A_c + softmax over T3 --------------------------
  for (int p = t; p < 512; p += 256) {
    const int g = p >> 8, z = (p >> 4) & 15, wq = p & 15;
    const int xr = g*16 + z, yr = g*16 + wq;
    const char* xb = smb + FCQ_B + xr*256;
    const char* yb = smb + FCQ_B + yr*256;
    const int xs = (xr & 7) << 4, ys = (yr & 7) << 4;
    float s = 0.f;
    #pragma unroll
    for (int k = 0; k < DL_; k += 8) {
      short8_t xv = *(const short8_t*)(xb + ((k*2) ^ xs));
      short8_t yv = *(const short8_t*)(yb + ((k*2) ^ ys));
      s += b2f(xv[0])*b2f(yv[0]) + b2f(xv[1])*b2f(yv[1])
         + b2f(xv[2])*b2f(yv[2]) + b2f(xv[3])*b2f(yv[3])
         + b2f(xv[4])*b2f(yv[4]) + b2f(xv[5])*b2f(yv[5])
         + b2f(xv[6])*b2f(yv[6]) + b2f(xv[7])*b2f(yv[7]);
    }
    sAc[(g*16+z)*17 + wq] = s * inv_sqrt_dl;
  }
  __syncthreads();
  if (t < 32) {
    float* srow = sAc + t*17;
    float m = -1e30f;
    for (int wq = 0; wq < 16; ++wq) m = fmaxf(m, srow[wq]);
    float sum = 0.f;
    for (int wq = 0; wq < 16; ++wq) { float e = __expf(srow[wq]-m); srow[wq] = e; sum += e; }
    float inv = 1.f/sum;
    for (int wq = 0; wq < 16; ++wq) srow[wq] *= inv;
  }
  __syncthreads();
  // ---------------- phase5: f_cc_hat -> bf16 swizzled LDS (over FCQ) -------
  for (int p = t; p < 1024; p += 256) {
    const int r = p >> 5, d4 = (p & 31)*4;
    const int g = r >> 4, z = r & 15;
    float ax = 0.f, ay = 0.f, az = 0.f, aw = 0.f;
    #pragma unroll
    for (int wq = 0; wq < 16; ++wq) {
      float a = sAc[(g*16+z)*17 + wq];
      float4 f = *(const float4*)(sFch + (g*16+wq)*132 + d4);
      ax += a*f.x; ay += a*f.y; az += a*f.z; aw += a*f.w;
    }
    ushort4 pk;
    pk.x = f2b(ax); pk.y = f2b(ay); pk.z = f2b(az); pk.w = f2b(aw);
    *(ushort4*)(smb + FCQ_B + r*256 + ((d4*2) ^ ((r & 7) << 4))) = pk;
  }
  __syncthreads();

  // ---------------- up GEMM + vectorized epilogue (no barriers) ------------
  {
    const int fcr2 = wr + l15;                 // local row 0..31
    const char* fcqrow = smb + FCQ_B + fcr2*256;
    const int xsw = (fcr2 & 7) << 4;
    const int grow = row0 + wr + l15;
    const size_t obase = (size_t)grow * D_;
    const size_t mbase = (size_t)(grow >> 4) * D_;
    for (int ch = 0; ch < 8; ++ch) {
      f32x4 uacc[2]; uacc[0] = z4; uacc[1] = z4;
      #pragma unroll
      for (int ks = 0; ks < 4; ++ks) {
        short8_t bfrag = *(const short8_t*)(fcqrow + ((ks*64 + l4*16) ^ xsw));
        #pragma unroll
        for (int cf = 0; cf < 2; ++cf) {
          const int d = ch*64 + wc*32 + cf*16 + l15;
          short8_t afrag = *(const short8_t*)(wub + (size_t)d*DL_ + ks*32 + l4*8);
          uacc[cf] = __builtin_amdgcn_mfma_f32_16x16x32_bf16(afrag, bfrag, uacc[cf], 0, 0, 0);
        }
      }
      #pragma unroll
      for (int cf = 0; cf < 2; ++cf) {
        const int d0 = ch*64 + wc*32 + cf*16 + l4*4;
        float4 bias = *(const float4*)(bc_up + d0);
        float4 fs4 = *(const float4*)(f_s + (size_t)b*D_ + d0);
        float4 fm4 = *(const float4*)(f_m + mbase + d0);
        float4 fc4 = *(const float4*)(f_c + obase + d0);
        float4 o;
        o.x = uacc[cf][0] + bias.x + fc4.x + fm4.x/(1.f + __expf(-fm4.x*fs4.x));
        o.y = uacc[cf][1] + bias.y + fc4.y + fm4.y/(1.f + __expf(-fm4.y*fs4.y));
        o.z = uacc[cf][2] + bias.z + fc4.z + fm4.z/(1.f + __expf(-fm4.z*fs4.z));
        o.w = uacc[cf][3] + bias.w + fc4.w + fm4.w/(1.f + __expf(-fm4.w*fs4.w));
        *(float4*)(out + obase + d0) = o;
      }
    }
  }
}

extern "C" void kernel_launch(void* const* d_in, const int* in_sizes, int n_in,
                              void* d_out, int out_size, void* d_ws, size_t ws_size,
                              hipStream_t stream) {
  (void)in_sizes; (void)n_in; (void)out_size; (void)ws_size;
  const float* f_c     = (const float*)d_in[0];
  const float* f_w     = (const float*)d_in[1];
  const float* f_s     = (const float*)d_in[2];
  const float* f_m     = (const float*)d_in[3];
  const float* Wc_down = (const float*)d_in[4];
  const float* bc_down = (const float*)d_in[5];
  const float* Ww      = (const float*)d_in[6];
  const float* bw      = (const float*)d_in[7];
  const float* Ws      = (const float*)d_in[8];
  const float* bs      = (const float*)d_in[9];
  const float* Wq      = (const float*)d_in[10];
  const float* bq      = (const float*)d_in[11];
  const float* Wk      = (const float*)d_in[12];
  const float* bk      = (const float*)d_in[13];
  const float* Wc_up   = (const float*)d_in[14];
  const float* bc_up   = (const float*)d_in[15];
  float* out = (float*)d_out;
  float* wsf = (float*)d_ws;
  unsigned short* wdb = (unsigned short*)(wsf + WS_WDB);
  unsigned short* wub = (unsigned short*)(wsf + WS_WUB);

  hipLaunchKernelGGL(k0_convert, dim3(128), dim3(256), 0, stream,
                     Wc_down, Wc_up, wdb, wub);
  hipLaunchKernelGGL(k1_small, dim3(B_*L_), dim3(128), 0, stream,
                     f_w, f_s, Ww, bw, Ws, bs, Wq, bq, Wk, bk, wsf);
  hipLaunchKernelGGL(k2_fused, dim3(M_/32), dim3(256), 0, stream,
                     f_c, wdb, wub, bc_down, bc_up, f_m, f_s, wsf, out);
}